// Round 6
// baseline (29911.407 us; speedup 1.0000x reference)
//
#include <hip/hip_runtime.h>

#define S_LEN 1024
#define BATCH 128
#define HID 1024
#define OBS 64

typedef __attribute__((ext_vector_type(8))) short short8;
typedef __attribute__((ext_vector_type(4))) float f32x4;

__device__ __forceinline__ unsigned short f2bf(float f) {
  union { float f; unsigned int u; } a; a.f = f;
  unsigned int r = a.u + 0x7FFF + ((a.u >> 16) & 1);
  return (unsigned short)(r >> 16);
}
__device__ __forceinline__ float sigf(float x) { return 1.0f / (1.0f + __expf(-x)); }
__device__ __forceinline__ float tanhf_(float x) { return 1.0f - 2.0f / (__expf(2.0f * x) + 1.0f); }

// ---------------- packing kernels ----------------
// xP layout: [t][btg(8)][kc(2)][lane(64)][8]  (A-fragment layout, k = x-dim 0..63)
__global__ void pack_x_kernel(const float* __restrict__ x, unsigned short* __restrict__ xP) {
  int gid = blockIdx.x * 256 + threadIdx.x;   // 1,048,576 total (exact)
  int lane = gid & 63, kc = (gid >> 6) & 1, bt = (gid >> 7) & 7, t = gid >> 10;
  int b = bt * 16 + (lane & 15);
  int k0 = kc * 32 + 8 * (lane >> 4);
  const float* src = x + (size_t)t * (BATCH * OBS) + b * OBS + k0;
  unsigned short v[8];
#pragma unroll
  for (int j = 0; j < 8; ++j) v[j] = f2bf(src[j]);
  *(uint4*)(xP + (size_t)gid * 8) = *(const uint4*)v;
}

// Wp layout: [coltile(256)][kc(nkc)][lane(64)][8] ; B[k][col], col = ct*16+(lane&15), k = kc*32+8*(lane>>4)+j
__global__ void pack_w_kernel(const float* __restrict__ W, unsigned short* __restrict__ Wp, int nkc) {
  int gid = blockIdx.x * 256 + threadIdx.x;   // valid range: 256*nkc*64
  if (gid >= 256 * 64 * nkc) return;          // guard: grid may overshoot (OOB fix)
  int lane = gid & 63;
  int kc = (gid >> 6) % nkc;
  int ct = gid / (64 * nkc);
  int col = ct * 16 + (lane & 15);
  int k0 = kc * 32 + 8 * (lane >> 4);
  const float* src = W + (size_t)k0 * 4096 + col;
  unsigned short v[8];
#pragma unroll
  for (int j = 0; j < 8; ++j) v[j] = f2bf(src[(size_t)j * 4096]);
  *(uint4*)(Wp + (size_t)gid * 8) = *(const uint4*)v;
}

// ---------------- GEMM tile (32b x 16u per WG, wave g = gate g) ----------------
// A1/A2/hP frag layouts: [btg][kc][lane][8]; Wp: [coltile][kc][lane][8]
template <int NKA, int NKB>
__device__ __forceinline__ void gemm_tile(const unsigned short* __restrict__ A1,
                                          const unsigned short* __restrict__ A2,
                                          const unsigned short* __restrict__ Wp,
                                          int coltile, int btg0, int lane,
                                          f32x4& acc0, f32x4& acc1) {
  constexpr int NK = NKA + NKB;
  const short8* a1p0 = (const short8*)A1 + (size_t)(btg0)     * NKA * 64 + lane;
  const short8* a1p1 = (const short8*)A1 + (size_t)(btg0 + 1) * NKA * 64 + lane;
  const short8* a2p0 = (const short8*)A2 + (size_t)(btg0)     * NKB * 64 + lane;
  const short8* a2p1 = (const short8*)A2 + (size_t)(btg0 + 1) * NKB * 64 + lane;
  const short8* bp   = (const short8*)Wp + (size_t)coltile * NK * 64 + lane;
#pragma unroll 2
  for (int kc = 0; kc < NKA; ++kc) {
    short8 bfr = bp[kc * 64];
    acc0 = __builtin_amdgcn_mfma_f32_16x16x32_bf16(a1p0[kc * 64], bfr, acc0, 0, 0, 0);
    acc1 = __builtin_amdgcn_mfma_f32_16x16x32_bf16(a1p1[kc * 64], bfr, acc1, 0, 0, 0);
  }
#pragma unroll 4
  for (int kc = 0; kc < NKB; ++kc) {
    short8 bfr = bp[(NKA + kc) * 64];
    acc0 = __builtin_amdgcn_mfma_f32_16x16x32_bf16(a2p0[kc * 64], bfr, acc0, 0, 0, 0);
    acc1 = __builtin_amdgcn_mfma_f32_16x16x32_bf16(a2p1[kc * 64], bfr, acc1, 0, 0, 0);
  }
}

// LSTM cell update; writes c (fp32) and h in fragment layout (bf16)
__device__ __forceinline__ void update_phase(int bt32, int ut, int tid,
                                             const float (*zb)[32][17],
                                             const float* __restrict__ bz,
                                             const float* __restrict__ c_in,
                                             float* __restrict__ c_out,
                                             unsigned short* __restrict__ hPout) {
#pragma unroll
  for (int i = tid; i < 512; i += 256) {
    int row = i >> 4, col = i & 15;
    int b = bt32 * 32 + row, u = ut * 16 + col;
    float zi = zb[0][row][col] + bz[u];
    float zj = zb[1][row][col] + bz[HID + u];
    float zf = zb[2][row][col] + bz[2 * HID + u];
    float zo = zb[3][row][col] + bz[3 * HID + u];
    float cold = c_in[b * HID + u];
    float cn = sigf(zf + 1.0f) * cold + sigf(zi) * tanhf_(zj);
    c_out[b * HID + u] = cn;
    float hn = sigf(zo) * tanhf_(cn);
    int btg = b >> 4;
    int fidx = ((btg * 32 + (u >> 5)) * 64 + ((u >> 3) & 3) * 16 + (b & 15)) * 8 + (u & 7);
    hPout[fidx] = f2bf(hn);
  }
}

// inp = tanh(x @ W_s + b_s), written in fragment layout (for next step's A operand)
__device__ __forceinline__ void inp_phase(int wg, int tid, const float* __restrict__ x,
                                          const float* __restrict__ W_s,
                                          const float* __restrict__ b_s,
                                          unsigned short* __restrict__ out) {
  int oidx = wg * 512 + tid * 2;   // 256 WGs * 512 = 131072 outputs
  int b = oidx >> 10, u = oidx & 1023;   // u even
  float a0 = b_s[u], a1 = b_s[u + 1];
  const float* xr = x + b * OBS;
#pragma unroll 8
  for (int k = 0; k < OBS; ++k) {
    float xv = xr[k];
    a0 = fmaf(xv, W_s[k * HID + u], a0);
    a1 = fmaf(xv, W_s[k * HID + u + 1], a1);
  }
  a0 = tanhf_(a0); a1 = tanhf_(a1);
  unsigned int vv = (unsigned int)f2bf(a0) | ((unsigned int)f2bf(a1) << 16);
  int btg = b >> 4;
  int base = ((btg * 32 + (u >> 5)) * 64 + ((u >> 3) & 3) * 16 + (b & 15)) * 8 + (u & 7);
  *(unsigned int*)(out + base) = vv;
}

// out_row[b][o] = c_in[b] @ W_o + b_o ; per WG: b = wg>>2 (and b+64), o-block = (wg&3)*16
__device__ __forceinline__ void proj_phase(int wg, int tid, const float* __restrict__ c_in,
                                           const float* __restrict__ W_o,
                                           const float* __restrict__ b_o,
                                           float* __restrict__ outrow,
                                           float* __restrict__ red /*128 floats*/) {
  int b = wg >> 2;
  int o = (wg & 3) * 16 + (tid & 15);
  int ks = tid >> 4;   // 16-way K split, 64 k each
  const float* cr0 = c_in + b * HID + ks * 64;
  const float* cr1 = cr0 + 64 * HID;
  float s0 = 0.f, s1 = 0.f;
#pragma unroll 8
  for (int k = 0; k < 64; ++k) {
    float wv = W_o[(ks * 64 + k) * OBS + o];
    s0 = fmaf(cr0[k], wv, s0);
    s1 = fmaf(cr1[k], wv, s1);
  }
  s0 += __shfl_xor(s0, 16); s0 += __shfl_xor(s0, 32);
  s1 += __shfl_xor(s1, 16); s1 += __shfl_xor(s1, 32);
  int wv_ = tid >> 6;
  if ((tid & 48) == 0) {
    red[(0 * 4 + wv_) * 16 + (tid & 15)] = s0;
    red[(1 * 4 + wv_) * 16 + (tid & 15)] = s1;
  }
  __syncthreads();
  if (tid < 32) {
    int half = tid >> 4, ol = tid & 15;
    float s = red[(half * 4 + 0) * 16 + ol] + red[(half * 4 + 1) * 16 + ol] +
              red[(half * 4 + 2) * 16 + ol] + red[(half * 4 + 3) * 16 + ol];
    int oo = (wg & 3) * 16 + ol;
    outrow[(b + half * 64) * OBS + oo] = s + b_o[oo];
  }
}

// ---------------- step kernels ----------------
__global__ __launch_bounds__(256) void enc_step_kernel(
    const unsigned short* __restrict__ xPt, const unsigned short* __restrict__ hPin,
    unsigned short* __restrict__ hPout, float* __restrict__ c,
    const unsigned short* __restrict__ wpe, const float* __restrict__ b_enc,
    const float* __restrict__ xnext, const float* __restrict__ W_s,
    const float* __restrict__ b_s, unsigned short* __restrict__ inpPout) {
  __shared__ float zb[4][32][17];
  int tid = threadIdx.x, wg = blockIdx.x;
  int lane = tid & 63, g = tid >> 6;
  int ut = (wg & 7) * 8 + ((wg >> 3) & 7);   // XCD-swizzled unit-tile
  int bt32 = wg >> 6;
  f32x4 acc0 = {0.f, 0.f, 0.f, 0.f}, acc1 = {0.f, 0.f, 0.f, 0.f};
  gemm_tile<2, 32>(xPt, hPin, wpe, ut + g * 64, bt32 * 2, lane, acc0, acc1);
  int r4 = (lane >> 4) * 4, col = lane & 15;
#pragma unroll
  for (int r = 0; r < 4; ++r) { zb[g][r4 + r][col] = acc0[r]; zb[g][16 + r4 + r][col] = acc1[r]; }
  __syncthreads();
  update_phase(bt32, ut, tid, zb, b_enc, c, c, hPout);
  if (inpPout) inp_phase(wg, tid, xnext, W_s, b_s, inpPout);
}

__global__ __launch_bounds__(256) void dec_step_kernel(
    const unsigned short* __restrict__ inpPin, const unsigned short* __restrict__ hPin,
    unsigned short* __restrict__ hPout, const float* __restrict__ c_in,
    float* __restrict__ c_out, const unsigned short* __restrict__ wpd,
    const float* __restrict__ b_dec, const float* __restrict__ xnext,
    const float* __restrict__ W_s, const float* __restrict__ b_s,
    unsigned short* __restrict__ inpPout, const float* __restrict__ W_o,
    const float* __restrict__ b_o, float* __restrict__ outrow) {
  __shared__ float zb[4][32][17];
  __shared__ float red[128];
  int tid = threadIdx.x, wg = blockIdx.x;
  int lane = tid & 63, g = tid >> 6;
  int ut = (wg & 7) * 8 + ((wg >> 3) & 7);
  int bt32 = wg >> 6;
  f32x4 acc0 = {0.f, 0.f, 0.f, 0.f}, acc1 = {0.f, 0.f, 0.f, 0.f};
  gemm_tile<32, 32>(inpPin, hPin, wpd, ut + g * 64, bt32 * 2, lane, acc0, acc1);
  int r4 = (lane >> 4) * 4, col = lane & 15;
#pragma unroll
  for (int r = 0; r < 4; ++r) { zb[g][r4 + r][col] = acc0[r]; zb[g][16 + r4 + r][col] = acc1[r]; }
  __syncthreads();
  update_phase(bt32, ut, tid, zb, b_dec, c_in, c_out, hPout);
  inp_phase(wg, tid, xnext, W_s, b_s, inpPout);
  proj_phase(wg, tid, c_in, W_o, b_o, outrow, red);
}

__global__ __launch_bounds__(256) void proj_kernel(const float* __restrict__ c_in,
                                                   const float* __restrict__ W_o,
                                                   const float* __restrict__ b_o,
                                                   float* __restrict__ outrow) {
  __shared__ float red[128];
  proj_phase(blockIdx.x, threadIdx.x, c_in, W_o, b_o, outrow, red);
}

// ---------------- launcher ----------------
extern "C" void kernel_launch(void* const* d_in, const int* in_sizes, int n_in,
                              void* d_out, int out_size, void* d_ws, size_t ws_size,
                              hipStream_t stream) {
  const float* x     = (const float*)d_in[0];
  const float* W_enc = (const float*)d_in[1];
  const float* b_enc = (const float*)d_in[2];
  const float* W_dec = (const float*)d_in[3];
  const float* b_dec = (const float*)d_in[4];
  const float* W_s   = (const float*)d_in[5];
  const float* b_s   = (const float*)d_in[6];
  const float* W_o   = (const float*)d_in[7];
  const float* b_o   = (const float*)d_in[8];
  float* out = (float*)d_out;

  // workspace carve (needs ~46 MB)
  unsigned short* xP  = (unsigned short*)d_ws;          // 8,388,608 ush
  unsigned short* wpe = xP + 8388608;                   // 4,456,448 ush
  unsigned short* wpd = wpe + 4456448;                  // 8,388,608 ush
  unsigned short* hP0 = wpd + 8388608;                  // 131,072 ush
  unsigned short* hP1 = hP0 + 131072;
  unsigned short* iP0 = hP1 + 131072;
  unsigned short* iP1 = iP0 + 131072;
  float* c0 = (float*)(iP1 + 131072);                   // 131,072 f32
  float* c1 = c0 + 131072;

  hipLaunchKernelGGL(pack_x_kernel, dim3(4096), dim3(256), 0, stream, x, xP);
  hipLaunchKernelGGL(pack_w_kernel, dim3(2176), dim3(256), 0, stream, W_enc, wpe, 34);
  hipLaunchKernelGGL(pack_w_kernel, dim3(4096), dim3(256), 0, stream, W_dec, wpd, 64);
  hipMemsetAsync(hP0, 0, 131072 * sizeof(unsigned short), stream);
  hipMemsetAsync(c0, 0, 131072 * sizeof(float), stream);

  // encoder: t = 0..1023; h ping-pong, c in place; last step computes inp for dec step 0
  for (int t = 0; t < 1024; ++t) {
    unsigned short* hin  = (t & 1) ? hP1 : hP0;
    unsigned short* hout = (t & 1) ? hP0 : hP1;
    bool last = (t == 1023);
    hipLaunchKernelGGL(enc_step_kernel, dim3(256), dim3(256), 0, stream,
                       xP + (size_t)t * 8192, hin, hout, c0, wpe, b_enc,
                       x + (size_t)1023 * 8192, W_s, b_s,
                       last ? iP0 : (unsigned short*)nullptr);
  }
  // decoder: k = 0..1022 processes x_t with t = 1023-k.
  //  - kernel k also computes inp for step k+1 (from x_{1022-k})
  //  - kernel k projects the PREVIOUS c (c_in) to out row 1023-k  (k=0: c_f -> row 1023)
  for (int k = 0; k < 1023; ++k) {
    unsigned short* hin  = (k & 1) ? hP1 : hP0;
    unsigned short* hout = (k & 1) ? hP0 : hP1;
    const float* cin     = (k & 1) ? c1 : c0;
    float* cout          = (k & 1) ? c0 : c1;
    unsigned short* iin  = (k & 1) ? iP1 : iP0;
    unsigned short* iout = (k & 1) ? iP0 : iP1;
    hipLaunchKernelGGL(dec_step_kernel, dim3(256), dim3(256), 0, stream,
                       iin, hin, hout, cin, cout, wpd, b_dec,
                       x + (size_t)(1022 - k) * 8192, W_s, b_s, iout, W_o, b_o,
                       out + (size_t)(1023 - k) * 8192);
  }
  // final projection: c after step k=1022 (in c1) -> out row 0
  hipLaunchKernelGGL(proj_kernel, dim3(256), dim3(256), 0, stream, c1, W_o, b_o, out);
}